// Round 3
// baseline (237.833 us; speedup 1.0000x reference)
//
#include <hip/hip_runtime.h>
#include <math.h>

// B=4, N=128, H=W=32, C=64.  out[b][j][n] = sigmoid(wl[j,:] . mean_hw MLP(...) + bl[j])
//
// MFMA formulation: per (b,n), layers 2..5 are 64x64 GEMMs over 1024 pixel
// columns -> v_mfma_f32_16x16x32_bf16, M=64(ch) x N=32(px) x K=64 tiles.
// Layer 1 (7->64) is the same MFMA with K=32 zero-padded.
// R3: 512 blocks x 512 thr (8 waves) -> 4 waves/SIMD (was 2). Wave owns 4
// tiles of 32 px. Weights stream from L1/L2 per tile (compiler sinks the
// "preload" loads into the loop; VGPR=128). No mid-kernel barriers.
// Activation layout transform C-layout -> B-layout via 4KB/wave LDS:
//   C: col=lane&15, row=(lane>>4)*4+reg   [m89-verified]
//   A/B: n=lane&15, k=(lane>>4)*8+j        [m120-verified]

typedef float  f32x4  __attribute__((ext_vector_type(4)));
typedef f32x4  f32x4a __attribute__((may_alias));
typedef __bf16 bf16x8 __attribute__((ext_vector_type(8)));
typedef bf16x8 bf16x8a __attribute__((may_alias));
typedef __bf16 bf16x4 __attribute__((ext_vector_type(4)));
typedef bf16x4 bf16x4a __attribute__((may_alias));
typedef float  floata __attribute__((may_alias));

#define MFMA16(a, b, c) __builtin_amdgcn_mfma_f32_16x16x32_bf16((a), (b), (c), 0, 0, 0)

__global__ __launch_bounds__(512, 4) void mlp_mfma_kernel(
    const float* __restrict__ image,   // [4,3,32,32]
    const float* __restrict__ coords,  // [4,128,2]
    const float* __restrict__ w1, const float* __restrict__ b1,   // [64,7],[64]
    const float* __restrict__ w2, const float* __restrict__ b2,   // [64,64],[64]
    const float* __restrict__ w3, const float* __restrict__ b3,
    const float* __restrict__ w4, const float* __restrict__ b4,
    const float* __restrict__ w5, const float* __restrict__ b5,
    const float* __restrict__ wl, const float* __restrict__ bl,   // [3,64],[3]
    float* __restrict__ out)           // [4,3,128]
{
    __shared__ __align__(16) __bf16 Xs[8][2048];   // 4KB per wave: B-frag ping-pong

    const int tid  = threadIdx.x;
    const int wave = tid >> 6;
    const int lane = tid & 63;
    const int c15  = lane & 15;
    const int q    = lane >> 4;
    const int bn   = blockIdx.x;
    const int b    = bn >> 7;

    __bf16* Xw = &Xs[wave][0];

    const float cx = coords[2 * bn + 0];
    const float cy = coords[2 * bn + 1];

    // ---- W2..W5 A-fragments (compiler sinks these loads into the tile loop;
    //      they hit L1/L2 — do NOT force them resident, VGPR budget is 128)
    const float* Ws[4] = {w2, w3, w4, w5};
    const float* Bs[4] = {b2, b3, b4, b5};
    bf16x8 wf[4][4][2];
    #pragma unroll
    for (int l = 0; l < 4; ++l)
        #pragma unroll
        for (int mt = 0; mt < 4; ++mt)
            #pragma unroll
            for (int ks = 0; ks < 2; ++ks) {
                const float* src = Ws[l] + (mt * 16 + c15) * 64 + ks * 32 + q * 8;
                f32x4 lo = *(const f32x4a*)src;
                f32x4 hi = *(const f32x4a*)(src + 4);
                bf16x8 f;
                f[0] = (__bf16)lo[0]; f[1] = (__bf16)lo[1];
                f[2] = (__bf16)lo[2]; f[3] = (__bf16)lo[3];
                f[4] = (__bf16)hi[0]; f[5] = (__bf16)hi[1];
                f[6] = (__bf16)hi[2]; f[7] = (__bf16)hi[3];
                wf[l][mt][ks] = f;
            }

    // ---- W1 A-frags: K=32 zero-padded (valid only q==0, k<7)
    const float qm = (q == 0) ? 1.0f : 0.0f;
    bf16x8 w1f[4];
    #pragma unroll
    for (int mt = 0; mt < 4; ++mt) {
        const int o = mt * 16 + c15;
        bf16x8 f;
        #pragma unroll
        for (int j = 0; j < 7; ++j)
            f[j] = (__bf16)(qm * w1[o * 7 + j]);
        f[7] = (__bf16)0.0f;
        w1f[mt] = f;
    }

    const float* img = image + b * 3072;
    // per-lane halfword offset of the transform write
    const int lane_woff = c15 * 8 + (q >> 1) * 128 + (q & 1) * 4;

    f32x4 pool[4];
    #pragma unroll
    for (int mt = 0; mt < 4; ++mt) pool[mt] = (f32x4){0.f, 0.f, 0.f, 0.f};

    const int wbase = wave * 128;   // 8 waves x 128 px

    // epilogue: leaky + cvt bf16 + C->B layout transform into LDS
    auto store_x = [&](f32x4 (&acc)[4][2]) {
        #pragma unroll
        for (int mt = 0; mt < 4; ++mt)
            #pragma unroll
            for (int nt = 0; nt < 2; ++nt) {
                f32x4 a = acc[mt][nt];
                bf16x4 p;
                #pragma unroll
                for (int r = 0; r < 4; ++r) {
                    float v = fmaxf(a[r], 0.1f * a[r]);   // leaky (slope<1)
                    p[r] = (__bf16)v;
                }
                const int off = (nt * 2 + (mt >> 1)) * 512 + (mt & 1) * 256 + lane_woff;
                *(bf16x4a*)&Xw[off] = p;
            }
    };

    #pragma unroll 1
    for (int t = 0; t < 4; ++t) {
        // ---- layer 1: build feature B-frags directly in registers
        bf16x8 bft[2];
        #pragma unroll
        for (int nt = 0; nt < 2; ++nt) {
            const int hw = wbase + t * 32 + nt * 16 + c15;
            const float i0 = img[hw];
            const float i1 = img[1024 + hw];
            const float i2 = img[2048 + hw];
            bf16x8 f;
            f[0] = (__bf16)(qm * i0);
            f[1] = (__bf16)(qm * i1);
            f[2] = (__bf16)(qm * i2);
            f[3] = (__bf16)(qm * (float)(hw >> 5) * (1.0f / 31.0f));
            f[4] = (__bf16)(qm * (float)(hw & 31) * (1.0f / 31.0f));
            f[5] = (__bf16)(qm * cx);
            f[6] = (__bf16)(qm * cy);
            f[7] = (__bf16)0.0f;
            bft[nt] = f;
        }

        f32x4 acc[4][2];
        #pragma unroll
        for (int mt = 0; mt < 4; ++mt) {
            f32x4 bv = *(const f32x4a*)(b1 + mt * 16 + 4 * q);
            acc[mt][0] = bv; acc[mt][1] = bv;
        }
        #pragma unroll
        for (int mt = 0; mt < 4; ++mt)
            #pragma unroll
            for (int nt = 0; nt < 2; ++nt)
                acc[mt][nt] = MFMA16(w1f[mt], bft[nt], acc[mt][nt]);
        store_x(acc);

        // ---- layers 2..5
        #pragma unroll
        for (int l = 0; l < 4; ++l) {
            bf16x8 bf[2][2];
            #pragma unroll
            for (int nt = 0; nt < 2; ++nt)
                #pragma unroll
                for (int ks = 0; ks < 2; ++ks)
                    bf[nt][ks] = *(const bf16x8a*)&Xw[((nt * 2 + ks) * 64 + lane) * 8];
            #pragma unroll
            for (int mt = 0; mt < 4; ++mt) {
                f32x4 bv = *(const f32x4a*)(Bs[l] + mt * 16 + 4 * q);
                acc[mt][0] = bv; acc[mt][1] = bv;
            }
            #pragma unroll
            for (int mt = 0; mt < 4; ++mt)
                #pragma unroll
                for (int nt = 0; nt < 2; ++nt)
                    #pragma unroll
                    for (int ks = 0; ks < 2; ++ks)
                        acc[mt][nt] = MFMA16(wf[l][mt][ks], bf[nt][ks], acc[mt][nt]);
            if (l < 3) {
                store_x(acc);
            } else {
                // layer 5: leaky + pool accumulate (fp32)
                #pragma unroll
                for (int mt = 0; mt < 4; ++mt)
                    #pragma unroll
                    for (int nt = 0; nt < 2; ++nt) {
                        f32x4 a = acc[mt][nt];
                        #pragma unroll
                        for (int r = 0; r < 4; ++r)
                            pool[mt][r] += fmaxf(a[r], 0.1f * a[r]);
                    }
            }
        }
    }

    // ---- pool partials -> float view of (now free) X region: [ch][col16]
    floata* Xf = (floata*)Xw;
    #pragma unroll
    for (int mt = 0; mt < 4; ++mt)
        #pragma unroll
        for (int r = 0; r < 4; ++r)
            Xf[(mt * 16 + 4 * q + r) * 16 + c15] = pool[mt][r];

    __syncthreads();

    // ---- block reduce (8 waves x 16 cols) + head + sigmoid (wave 0 only)
    if (tid < 64) {
        const int c = tid;
        float s = 0.0f;
        #pragma unroll
        for (int w = 0; w < 8; ++w) {
            const floata* P = (const floata*)&Xs[w][0];
            #pragma unroll
            for (int c4 = 0; c4 < 4; ++c4) {
                f32x4 v = *(const f32x4a*)&P[c * 16 + c4 * 4];
                s += v[0] + v[1] + v[2] + v[3];
            }
        }
        const float p = s * (1.0f / 1024.0f);
        float s0 = wl[c] * p;
        float s1 = wl[64 + c] * p;
        float s2 = wl[128 + c] * p;
        #pragma unroll
        for (int off = 32; off > 0; off >>= 1) {
            s0 += __shfl_down(s0, off, 64);
            s1 += __shfl_down(s1, off, 64);
            s2 += __shfl_down(s2, off, 64);
        }
        if (c == 0) {
            const int n = bn & 127;
            out[(b * 3 + 0) * 128 + n] = 1.0f / (1.0f + expf(-(bl[0] + s0)));
            out[(b * 3 + 1) * 128 + n] = 1.0f / (1.0f + expf(-(bl[1] + s1)));
            out[(b * 3 + 2) * 128 + n] = 1.0f / (1.0f + expf(-(bl[2] + s2)));
        }
    }
}

extern "C" void kernel_launch(void* const* d_in, const int* in_sizes, int n_in,
                              void* d_out, int out_size, void* d_ws, size_t ws_size,
                              hipStream_t stream) {
    const float* image  = (const float*)d_in[0];
    const float* coords = (const float*)d_in[1];
    const float* w1 = (const float*)d_in[2];
    const float* b1 = (const float*)d_in[3];
    const float* w2 = (const float*)d_in[4];
    const float* b2 = (const float*)d_in[5];
    const float* w3 = (const float*)d_in[6];
    const float* b3 = (const float*)d_in[7];
    const float* w4 = (const float*)d_in[8];
    const float* b4 = (const float*)d_in[9];
    const float* w5 = (const float*)d_in[10];
    const float* b5 = (const float*)d_in[11];
    const float* wl = (const float*)d_in[12];
    const float* bl = (const float*)d_in[13];
    float* out = (float*)d_out;

    mlp_mfma_kernel<<<dim3(512), dim3(512), 0, stream>>>(
        image, coords, w1, b1, w2, b2, w3, b3, w4, b4, w5, b5, wl, bl, out);
}

// Round 4
// 154.073 us; speedup vs baseline: 1.5436x; 1.5436x over previous
//
#include <hip/hip_runtime.h>
#include <math.h>

// B=4, N=128, H=W=32, C=64.  out[b][j][n] = sigmoid(wl[j,:] . mean_hw MLP(...) + bl[j])
//
// MFMA formulation: per (b,n), layers 2..5 are 64x64 GEMMs over 1024 pixel
// columns -> v_mfma_f32_16x16x32_bf16, M=64(ch) x N=32(px) x K=64 tiles.
// Layer 1 (7->64) is the same MFMA with K=32 zero-padded.
// R4: 512 blocks x 512 thr (8 waves), __launch_bounds__(512,2).
//   R3 POST-MORTEM: (512,4) capped VGPR at 64 (2nd arg behaved as blocks/CU:
//   4 blk x 8 waves = 8 waves/SIMD -> 512/8 = 64) => massive scratch spill
//   (FETCH 372MB, WRITE 187MB, 164us). (512,2) -> 4 waves/SIMD -> 128 VGPR,
//   which is the natural footprint (R2 compiled to exactly 128, no spill).
// Weights stream from L1/L2 per tile. No mid-kernel barriers.
// Activation layout transform C-layout -> B-layout via 4KB/wave LDS:
//   C: col=lane&15, row=(lane>>4)*4+reg   [m89-verified]
//   A/B: n=lane&15, k=(lane>>4)*8+j        [m120-verified]

typedef float  f32x4  __attribute__((ext_vector_type(4)));
typedef f32x4  f32x4a __attribute__((may_alias));
typedef __bf16 bf16x8 __attribute__((ext_vector_type(8)));
typedef bf16x8 bf16x8a __attribute__((may_alias));
typedef __bf16 bf16x4 __attribute__((ext_vector_type(4)));
typedef bf16x4 bf16x4a __attribute__((may_alias));
typedef float  floata __attribute__((may_alias));

#define MFMA16(a, b, c) __builtin_amdgcn_mfma_f32_16x16x32_bf16((a), (b), (c), 0, 0, 0)

__global__ __launch_bounds__(512, 2) void mlp_mfma_kernel(
    const float* __restrict__ image,   // [4,3,32,32]
    const float* __restrict__ coords,  // [4,128,2]
    const float* __restrict__ w1, const float* __restrict__ b1,   // [64,7],[64]
    const float* __restrict__ w2, const float* __restrict__ b2,   // [64,64],[64]
    const float* __restrict__ w3, const float* __restrict__ b3,
    const float* __restrict__ w4, const float* __restrict__ b4,
    const float* __restrict__ w5, const float* __restrict__ b5,
    const float* __restrict__ wl, const float* __restrict__ bl,   // [3,64],[3]
    float* __restrict__ out)           // [4,3,128]
{
    __shared__ __align__(16) __bf16 Xs[8][2048];   // 4KB per wave: B-frag ping-pong

    const int tid  = threadIdx.x;
    const int wave = tid >> 6;
    const int lane = tid & 63;
    const int c15  = lane & 15;
    const int q    = lane >> 4;
    const int bn   = blockIdx.x;
    const int b    = bn >> 7;

    __bf16* Xw = &Xs[wave][0];

    const float cx = coords[2 * bn + 0];
    const float cy = coords[2 * bn + 1];

    // ---- W2..W5 A-fragments (compiler sinks these loads into the tile loop;
    //      they hit L1/L2 — VGPR budget is 128, do not force residency)
    const float* Ws[4] = {w2, w3, w4, w5};
    const float* Bs[4] = {b2, b3, b4, b5};
    bf16x8 wf[4][4][2];
    #pragma unroll
    for (int l = 0; l < 4; ++l)
        #pragma unroll
        for (int mt = 0; mt < 4; ++mt)
            #pragma unroll
            for (int ks = 0; ks < 2; ++ks) {
                const float* src = Ws[l] + (mt * 16 + c15) * 64 + ks * 32 + q * 8;
                f32x4 lo = *(const f32x4a*)src;
                f32x4 hi = *(const f32x4a*)(src + 4);
                bf16x8 f;
                f[0] = (__bf16)lo[0]; f[1] = (__bf16)lo[1];
                f[2] = (__bf16)lo[2]; f[3] = (__bf16)lo[3];
                f[4] = (__bf16)hi[0]; f[5] = (__bf16)hi[1];
                f[6] = (__bf16)hi[2]; f[7] = (__bf16)hi[3];
                wf[l][mt][ks] = f;
            }

    // ---- W1 A-frags: K=32 zero-padded (valid only q==0, k<7)
    const float qm = (q == 0) ? 1.0f : 0.0f;
    bf16x8 w1f[4];
    #pragma unroll
    for (int mt = 0; mt < 4; ++mt) {
        const int o = mt * 16 + c15;
        bf16x8 f;
        #pragma unroll
        for (int j = 0; j < 7; ++j)
            f[j] = (__bf16)(qm * w1[o * 7 + j]);
        f[7] = (__bf16)0.0f;
        w1f[mt] = f;
    }

    const float* img = image + b * 3072;
    // per-lane halfword offset of the transform write
    const int lane_woff = c15 * 8 + (q >> 1) * 128 + (q & 1) * 4;

    f32x4 pool[4];
    #pragma unroll
    for (int mt = 0; mt < 4; ++mt) pool[mt] = (f32x4){0.f, 0.f, 0.f, 0.f};

    const int wbase = wave * 128;   // 8 waves x 128 px

    // epilogue: leaky + cvt bf16 + C->B layout transform into LDS
    auto store_x = [&](f32x4 (&acc)[4][2]) {
        #pragma unroll
        for (int mt = 0; mt < 4; ++mt)
            #pragma unroll
            for (int nt = 0; nt < 2; ++nt) {
                f32x4 a = acc[mt][nt];
                bf16x4 p;
                #pragma unroll
                for (int r = 0; r < 4; ++r) {
                    float v = fmaxf(a[r], 0.1f * a[r]);   // leaky (slope<1)
                    p[r] = (__bf16)v;
                }
                const int off = (nt * 2 + (mt >> 1)) * 512 + (mt & 1) * 256 + lane_woff;
                *(bf16x4a*)&Xw[off] = p;
            }
    };

    #pragma unroll 1
    for (int t = 0; t < 4; ++t) {
        // ---- layer 1: build feature B-frags directly in registers
        bf16x8 bft[2];
        #pragma unroll
        for (int nt = 0; nt < 2; ++nt) {
            const int hw = wbase + t * 32 + nt * 16 + c15;
            const float i0 = img[hw];
            const float i1 = img[1024 + hw];
            const float i2 = img[2048 + hw];
            bf16x8 f;
            f[0] = (__bf16)(qm * i0);
            f[1] = (__bf16)(qm * i1);
            f[2] = (__bf16)(qm * i2);
            f[3] = (__bf16)(qm * (float)(hw >> 5) * (1.0f / 31.0f));
            f[4] = (__bf16)(qm * (float)(hw & 31) * (1.0f / 31.0f));
            f[5] = (__bf16)(qm * cx);
            f[6] = (__bf16)(qm * cy);
            f[7] = (__bf16)0.0f;
            bft[nt] = f;
        }

        f32x4 acc[4][2];
        #pragma unroll
        for (int mt = 0; mt < 4; ++mt) {
            f32x4 bv = *(const f32x4a*)(b1 + mt * 16 + 4 * q);
            acc[mt][0] = bv; acc[mt][1] = bv;
        }
        #pragma unroll
        for (int mt = 0; mt < 4; ++mt)
            #pragma unroll
            for (int nt = 0; nt < 2; ++nt)
                acc[mt][nt] = MFMA16(w1f[mt], bft[nt], acc[mt][nt]);
        store_x(acc);

        // ---- layers 2..5
        #pragma unroll
        for (int l = 0; l < 4; ++l) {
            bf16x8 bf[2][2];
            #pragma unroll
            for (int nt = 0; nt < 2; ++nt)
                #pragma unroll
                for (int ks = 0; ks < 2; ++ks)
                    bf[nt][ks] = *(const bf16x8a*)&Xw[((nt * 2 + ks) * 64 + lane) * 8];
            #pragma unroll
            for (int mt = 0; mt < 4; ++mt) {
                f32x4 bv = *(const f32x4a*)(Bs[l] + mt * 16 + 4 * q);
                acc[mt][0] = bv; acc[mt][1] = bv;
            }
            #pragma unroll
            for (int mt = 0; mt < 4; ++mt)
                #pragma unroll
                for (int nt = 0; nt < 2; ++nt)
                    #pragma unroll
                    for (int ks = 0; ks < 2; ++ks)
                        acc[mt][nt] = MFMA16(wf[l][mt][ks], bf[nt][ks], acc[mt][nt]);
            if (l < 3) {
                store_x(acc);
            } else {
                // layer 5: leaky + pool accumulate (fp32)
                #pragma unroll
                for (int mt = 0; mt < 4; ++mt)
                    #pragma unroll
                    for (int nt = 0; nt < 2; ++nt) {
                        f32x4 a = acc[mt][nt];
                        #pragma unroll
                        for (int r = 0; r < 4; ++r)
                            pool[mt][r] += fmaxf(a[r], 0.1f * a[r]);
                    }
            }
        }
    }

    // ---- pool partials -> float view of (now free) X region: [ch][col16]
    floata* Xf = (floata*)Xw;
    #pragma unroll
    for (int mt = 0; mt < 4; ++mt)
        #pragma unroll
        for (int r = 0; r < 4; ++r)
            Xf[(mt * 16 + 4 * q + r) * 16 + c15] = pool[mt][r];

    __syncthreads();

    // ---- block reduce (8 waves x 16 cols) + head + sigmoid (wave 0 only)
    if (tid < 64) {
        const int c = tid;
        float s = 0.0f;
        #pragma unroll
        for (int w = 0; w < 8; ++w) {
            const floata* P = (const floata*)&Xs[w][0];
            #pragma unroll
            for (int c4 = 0; c4 < 4; ++c4) {
                f32x4 v = *(const f32x4a*)&P[c * 16 + c4 * 4];
                s += v[0] + v[1] + v[2] + v[3];
            }
        }
        const float p = s * (1.0f / 1024.0f);
        float s0 = wl[c] * p;
        float s1 = wl[64 + c] * p;
        float s2 = wl[128 + c] * p;
        #pragma unroll
        for (int off = 32; off > 0; off >>= 1) {
            s0 += __shfl_down(s0, off, 64);
            s1 += __shfl_down(s1, off, 64);
            s2 += __shfl_down(s2, off, 64);
        }
        if (c == 0) {
            const int n = bn & 127;
            out[(b * 3 + 0) * 128 + n] = 1.0f / (1.0f + expf(-(bl[0] + s0)));
            out[(b * 3 + 1) * 128 + n] = 1.0f / (1.0f + expf(-(bl[1] + s1)));
            out[(b * 3 + 2) * 128 + n] = 1.0f / (1.0f + expf(-(bl[2] + s2)));
        }
    }
}

extern "C" void kernel_launch(void* const* d_in, const int* in_sizes, int n_in,
                              void* d_out, int out_size, void* d_ws, size_t ws_size,
                              hipStream_t stream) {
    const float* image  = (const float*)d_in[0];
    const float* coords = (const float*)d_in[1];
    const float* w1 = (const float*)d_in[2];
    const float* b1 = (const float*)d_in[3];
    const float* w2 = (const float*)d_in[4];
    const float* b2 = (const float*)d_in[5];
    const float* w3 = (const float*)d_in[6];
    const float* b3 = (const float*)d_in[7];
    const float* w4 = (const float*)d_in[8];
    const float* b4 = (const float*)d_in[9];
    const float* w5 = (const float*)d_in[10];
    const float* b5 = (const float*)d_in[11];
    const float* wl = (const float*)d_in[12];
    const float* bl = (const float*)d_in[13];
    float* out = (float*)d_out;

    mlp_mfma_kernel<<<dim3(512), dim3(512), 0, stream>>>(
        image, coords, w1, b1, w2, b2, w3, b3, w4, b4, w5, b5, wl, bl, out);
}

// Round 5
// 136.855 us; speedup vs baseline: 1.7378x; 1.1258x over previous
//
#include <hip/hip_runtime.h>
#include <math.h>

// B=4, N=128, H=W=32, C=64.  out[b][j][n] = sigmoid(wl[j,:] . mean_hw MLP(...) + bl[j])
//
// MFMA formulation: per (b,n), layers 2..5 are 64x64 GEMMs over 1024 pixel
// columns -> v_mfma_f32_16x16x32_bf16, M=64(ch) x N=32(px) x K=64 tiles.
// Layer 1 (7->64) is the same MFMA with K=32 zero-padded.
//
// R5: R2 config (512 blocks x 256 thr, launch_bounds(256,2) -> VGPR cap 256,
// 2 blocks/CU = 8 waves/CU) + WEIGHTS PINNED IN VGPRS via empty-asm.
//   R2/R4 POST-MORTEM: at VGPR=128 the compiler sinks all 32 weight-frag
//   loads (64 global f32x4 + ~300 cvt VALU) into every tile iteration —
//   that reload is the critical path (R4: doubling waves/SIMD only added L1
//   contention on streamed weights, 63->85us). Pin wf (128 VGPR) + w1f (16)
//   resident; loop body becomes ds_write -> ds_read -> MFMA.
//   R3 NOTE: launch_bounds 2nd arg acts as BLOCKS/CU here (observed VGPR=64
//   at (512,4)); (256,2) -> 8 waves/CU -> 256 VGPR budget.
// Activation layout transform C-layout -> B-layout via 4KB/wave LDS:
//   C: col=lane&15, row=(lane>>4)*4+reg   [m89-verified]
//   A/B: n=lane&15, k=(lane>>4)*8+j        [m120-verified]

typedef float  f32x4  __attribute__((ext_vector_type(4)));
typedef f32x4  f32x4a __attribute__((may_alias));
typedef __bf16 bf16x8 __attribute__((ext_vector_type(8)));
typedef bf16x8 bf16x8a __attribute__((may_alias));
typedef __bf16 bf16x4 __attribute__((ext_vector_type(4)));
typedef bf16x4 bf16x4a __attribute__((may_alias));
typedef float  floata __attribute__((may_alias));

#define MFMA16(a, b, c) __builtin_amdgcn_mfma_f32_16x16x32_bf16((a), (b), (c), 0, 0, 0)

__global__ __launch_bounds__(256, 2) void mlp_mfma_kernel(
    const float* __restrict__ image,   // [4,3,32,32]
    const float* __restrict__ coords,  // [4,128,2]
    const float* __restrict__ w1, const float* __restrict__ b1,   // [64,7],[64]
    const float* __restrict__ w2, const float* __restrict__ b2,   // [64,64],[64]
    const float* __restrict__ w3, const float* __restrict__ b3,
    const float* __restrict__ w4, const float* __restrict__ b4,
    const float* __restrict__ w5, const float* __restrict__ b5,
    const float* __restrict__ wl, const float* __restrict__ bl,   // [3,64],[3]
    float* __restrict__ out)           // [4,3,128]
{
    __shared__ __align__(16) __bf16 Xs[4][2048];   // 4KB per wave: B-frag ping-pong

    const int tid  = threadIdx.x;
    const int wave = tid >> 6;
    const int lane = tid & 63;
    const int c15  = lane & 15;
    const int q    = lane >> 4;
    const int bn   = blockIdx.x;
    const int b    = bn >> 7;

    __bf16* Xw = &Xs[wave][0];

    const float cx = coords[2 * bn + 0];
    const float cy = coords[2 * bn + 1];

    // ---- W2..W5 A-fragments, converted once and PINNED in VGPRs (128 regs)
    const float* Ws[4] = {w2, w3, w4, w5};
    const float* Bs[4] = {b2, b3, b4, b5};
    bf16x8 wf[4][4][2];
    #pragma unroll
    for (int l = 0; l < 4; ++l)
        #pragma unroll
        for (int mt = 0; mt < 4; ++mt)
            #pragma unroll
            for (int ks = 0; ks < 2; ++ks) {
                const float* src = Ws[l] + (mt * 16 + c15) * 64 + ks * 32 + q * 8;
                f32x4 lo = *(const f32x4a*)src;
                f32x4 hi = *(const f32x4a*)(src + 4);
                bf16x8 f;
                f[0] = (__bf16)lo[0]; f[1] = (__bf16)lo[1];
                f[2] = (__bf16)lo[2]; f[3] = (__bf16)lo[3];
                f[4] = (__bf16)hi[0]; f[5] = (__bf16)hi[1];
                f[6] = (__bf16)hi[2]; f[7] = (__bf16)hi[3];
                wf[l][mt][ks] = f;
            }

    // ---- W1 A-frags: K=32 zero-padded (valid only q==0, k<7), pinned (16 regs)
    const float qm = (q == 0) ? 1.0f : 0.0f;
    bf16x8 w1f[4];
    #pragma unroll
    for (int mt = 0; mt < 4; ++mt) {
        const int o = mt * 16 + c15;
        bf16x8 f;
        #pragma unroll
        for (int j = 0; j < 7; ++j)
            f[j] = (__bf16)(qm * w1[o * 7 + j]);
        f[7] = (__bf16)0.0f;
        w1f[mt] = f;
    }

    // Pin: opaque to the scheduler -> cannot rematerialize/sink the loads.
    #pragma unroll
    for (int l = 0; l < 4; ++l)
        #pragma unroll
        for (int mt = 0; mt < 4; ++mt)
            #pragma unroll
            for (int ks = 0; ks < 2; ++ks)
                asm volatile("" : "+v"(wf[l][mt][ks]));
    #pragma unroll
    for (int mt = 0; mt < 4; ++mt)
        asm volatile("" : "+v"(w1f[mt]));

    const float* img = image + b * 3072;
    // per-lane halfword offset of the transform write
    const int lane_woff = c15 * 8 + (q >> 1) * 128 + (q & 1) * 4;

    f32x4 pool[4];
    #pragma unroll
    for (int mt = 0; mt < 4; ++mt) pool[mt] = (f32x4){0.f, 0.f, 0.f, 0.f};

    const int wbase = wave * 256;

    // epilogue: leaky + cvt bf16 + C->B layout transform into LDS
    auto store_x = [&](f32x4 (&acc)[4][2]) {
        #pragma unroll
        for (int mt = 0; mt < 4; ++mt)
            #pragma unroll
            for (int nt = 0; nt < 2; ++nt) {
                f32x4 a = acc[mt][nt];
                bf16x4 p;
                #pragma unroll
                for (int r = 0; r < 4; ++r) {
                    float v = fmaxf(a[r], 0.1f * a[r]);   // leaky (slope<1)
                    p[r] = (__bf16)v;
                }
                const int off = (nt * 2 + (mt >> 1)) * 512 + (mt & 1) * 256 + lane_woff;
                *(bf16x4a*)&Xw[off] = p;
            }
    };

    #pragma unroll 1
    for (int t = 0; t < 8; ++t) {
        // ---- layer 1: build feature B-frags directly in registers
        bf16x8 bft[2];
        #pragma unroll
        for (int nt = 0; nt < 2; ++nt) {
            const int hw = wbase + t * 32 + nt * 16 + c15;
            const float i0 = img[hw];
            const float i1 = img[1024 + hw];
            const float i2 = img[2048 + hw];
            bf16x8 f;
            f[0] = (__bf16)(qm * i0);
            f[1] = (__bf16)(qm * i1);
            f[2] = (__bf16)(qm * i2);
            f[3] = (__bf16)(qm * (float)(hw >> 5) * (1.0f / 31.0f));
            f[4] = (__bf16)(qm * (float)(hw & 31) * (1.0f / 31.0f));
            f[5] = (__bf16)(qm * cx);
            f[6] = (__bf16)(qm * cy);
            f[7] = (__bf16)0.0f;
            bft[nt] = f;
        }

        f32x4 acc[4][2];
        #pragma unroll
        for (int mt = 0; mt < 4; ++mt) {
            f32x4 bv = *(const f32x4a*)(b1 + mt * 16 + 4 * q);
            acc[mt][0] = bv; acc[mt][1] = bv;
        }
        #pragma unroll
        for (int mt = 0; mt < 4; ++mt)
            #pragma unroll
            for (int nt = 0; nt < 2; ++nt)
                acc[mt][nt] = MFMA16(w1f[mt], bft[nt], acc[mt][nt]);
        store_x(acc);

        // ---- layers 2..5
        #pragma unroll
        for (int l = 0; l < 4; ++l) {
            bf16x8 bf[2][2];
            #pragma unroll
            for (int nt = 0; nt < 2; ++nt)
                #pragma unroll
                for (int ks = 0; ks < 2; ++ks)
                    bf[nt][ks] = *(const bf16x8a*)&Xw[((nt * 2 + ks) * 64 + lane) * 8];
            #pragma unroll
            for (int mt = 0; mt < 4; ++mt) {
                f32x4 bv = *(const f32x4a*)(Bs[l] + mt * 16 + 4 * q);
                acc[mt][0] = bv; acc[mt][1] = bv;
            }
            #pragma unroll
            for (int mt = 0; mt < 4; ++mt)
                #pragma unroll
                for (int nt = 0; nt < 2; ++nt)
                    #pragma unroll
                    for (int ks = 0; ks < 2; ++ks)
                        acc[mt][nt] = MFMA16(wf[l][mt][ks], bf[nt][ks], acc[mt][nt]);
            if (l < 3) {
                store_x(acc);
            } else {
                // layer 5: leaky + pool accumulate (fp32)
                #pragma unroll
                for (int mt = 0; mt < 4; ++mt)
                    #pragma unroll
                    for (int nt = 0; nt < 2; ++nt) {
                        f32x4 a = acc[mt][nt];
                        #pragma unroll
                        for (int r = 0; r < 4; ++r)
                            pool[mt][r] += fmaxf(a[r], 0.1f * a[r]);
                    }
            }
        }
    }

    // ---- pool partials -> float view of (now free) X region: [ch][col16]
    floata* Xf = (floata*)Xw;
    #pragma unroll
    for (int mt = 0; mt < 4; ++mt)
        #pragma unroll
        for (int r = 0; r < 4; ++r)
            Xf[(mt * 16 + 4 * q + r) * 16 + c15] = pool[mt][r];

    __syncthreads();

    // ---- block reduce (4 waves x 16 cols) + head + sigmoid (wave 0 only)
    if (tid < 64) {
        const int c = tid;
        float s = 0.0f;
        #pragma unroll
        for (int w = 0; w < 4; ++w) {
            const floata* P = (const floata*)&Xs[w][0];
            #pragma unroll
            for (int c4 = 0; c4 < 4; ++c4) {
                f32x4 v = *(const f32x4a*)&P[c * 16 + c4 * 4];
                s += v[0] + v[1] + v[2] + v[3];
            }
        }
        const float p = s * (1.0f / 1024.0f);
        float s0 = wl[c] * p;
        float s1 = wl[64 + c] * p;
        float s2 = wl[128 + c] * p;
        #pragma unroll
        for (int off = 32; off > 0; off >>= 1) {
            s0 += __shfl_down(s0, off, 64);
            s1 += __shfl_down(s1, off, 64);
            s2 += __shfl_down(s2, off, 64);
        }
        if (c == 0) {
            const int n = bn & 127;
            out[(b * 3 + 0) * 128 + n] = 1.0f / (1.0f + expf(-(bl[0] + s0)));
            out[(b * 3 + 1) * 128 + n] = 1.0f / (1.0f + expf(-(bl[1] + s1)));
            out[(b * 3 + 2) * 128 + n] = 1.0f / (1.0f + expf(-(bl[2] + s2)));
        }
    }
}

extern "C" void kernel_launch(void* const* d_in, const int* in_sizes, int n_in,
                              void* d_out, int out_size, void* d_ws, size_t ws_size,
                              hipStream_t stream) {
    const float* image  = (const float*)d_in[0];
    const float* coords = (const float*)d_in[1];
    const float* w1 = (const float*)d_in[2];
    const float* b1 = (const float*)d_in[3];
    const float* w2 = (const float*)d_in[4];
    const float* b2 = (const float*)d_in[5];
    const float* w3 = (const float*)d_in[6];
    const float* b3 = (const float*)d_in[7];
    const float* w4 = (const float*)d_in[8];
    const float* b4 = (const float*)d_in[9];
    const float* w5 = (const float*)d_in[10];
    const float* b5 = (const float*)d_in[11];
    const float* wl = (const float*)d_in[12];
    const float* bl = (const float*)d_in[13];
    float* out = (float*)d_out;

    mlp_mfma_kernel<<<dim3(512), dim3(256), 0, stream>>>(
        image, coords, w1, b1, w2, b2, w3, b3, w4, b4, w5, b5, wl, bl, out);
}

// Round 6
// 115.065 us; speedup vs baseline: 2.0670x; 1.1894x over previous
//
#include <hip/hip_runtime.h>
#include <math.h>

// B=4, N=128, H=W=32, C=64.  out[b][j][n] = sigmoid(wl[j,:] . mean_hw MLP(...) + bl[j])
//
// MFMA: layers 2..5 are 64x64 GEMMs over pixel columns (16x16x32_bf16,
// M=64ch x N=16px per MFMA); layer 1 (7->64) K=32 zero-padded.
//
// R6: WEIGHTS IN LDS. R2/R5 post-mortem: allocator refuses >128 arch VGPRs,
// spills weight frags to scratch (WRITE_SIZE 26MB = ~52 dwords/thread) and
// reloads per tile from L2 (~200+ cyc) — that reload was the critical path;
// the R5 asm-pin couldn't prevent spilling. Fix: bf16 A-frags staged once
// per block into LDS, lane-major (frag*1024B + lane*16B) => ds_read_b128 at
// the inherent-minimum bank pattern. Biases in LDS (broadcast = free).
// K-loop body = pure LDS. G=2 tiles (64px) per pass halves A-read traffic.
// DS-pipe model ~44K cyc/CU ≈ 18us floor.
// Act transform C->B via wave-private LDS (no barriers in main loop):
//   C: col=lane&15, row=(lane>>4)*4+reg   [m89-verified]
//   A/B: n=lane&15, k=(lane>>4)*8+j        [m120-verified]

typedef float  f32x4  __attribute__((ext_vector_type(4)));
typedef f32x4  f32x4a __attribute__((may_alias));
typedef __bf16 bf16x8 __attribute__((ext_vector_type(8)));
typedef bf16x8 bf16x8a __attribute__((may_alias));
typedef __bf16 bf16x4 __attribute__((ext_vector_type(4)));
typedef bf16x4 bf16x4a __attribute__((may_alias));
typedef float  floata __attribute__((may_alias));

#define MFMA16(a, b, c) __builtin_amdgcn_mfma_f32_16x16x32_bf16((a), (b), (c), 0, 0, 0)

// LDS halfword offsets
#define WL_H    0            // 36 frag-groups x 512 halfwords (36864 B)
#define ACT_H   18432        // 4 waves x 4096 halfwords (32768 B)

__global__ __launch_bounds__(256, 2) void mlp_mfma_kernel(
    const float* __restrict__ image,   // [4,3,32,32]
    const float* __restrict__ coords,  // [4,128,2]
    const float* __restrict__ w1, const float* __restrict__ b1,   // [64,7],[64]
    const float* __restrict__ w2, const float* __restrict__ b2,   // [64,64],[64]
    const float* __restrict__ w3, const float* __restrict__ b3,
    const float* __restrict__ w4, const float* __restrict__ b4,
    const float* __restrict__ w5, const float* __restrict__ b5,
    const float* __restrict__ wl, const float* __restrict__ bl,   // [3,64],[3]
    float* __restrict__ out)           // [4,3,128]
{
    __shared__ __align__(16) __bf16 LDSH[18432 + 16384];  // weights + acts
    __shared__ __align__(16) float  BL[320];              // biases [5][64]

    const int tid  = threadIdx.x;
    const int wave = tid >> 6;
    const int lane = tid & 63;
    const int c15  = lane & 15;
    const int q    = lane >> 4;
    const int bn   = blockIdx.x;
    const int b    = bn >> 7;

    const float qm = (q == 0) ? 1.0f : 0.0f;   // layer-1 K=32 zero-pad mask

    const float* Ws[4] = {w2, w3, w4, w5};

    // ---- stage weight A-frags into LDS, lane-major: frag id*512h + lane*8h
    //   id = l*8 + mt*2 + ks  (l=0..3 -> w2..w5), id = 32+mt -> w1
    #pragma unroll 1
    for (int i = 0; i < 9; ++i) {
        const int id = wave + i * 4;           // 4 waves cover 0..35
        __bf16* dst = &LDSH[WL_H + id * 512 + lane * 8];
        if (id < 32) {
            const int l  = id >> 3;
            const int mt = (id >> 1) & 3;
            const int ks = id & 1;
            const float* src = Ws[l] + (mt * 16 + c15) * 64 + ks * 32 + q * 8;
            f32x4 lo = *(const f32x4a*)src;
            f32x4 hi = *(const f32x4a*)(src + 4);
            bf16x8 f;
            f[0] = (__bf16)lo[0]; f[1] = (__bf16)lo[1];
            f[2] = (__bf16)lo[2]; f[3] = (__bf16)lo[3];
            f[4] = (__bf16)hi[0]; f[5] = (__bf16)hi[1];
            f[6] = (__bf16)hi[2]; f[7] = (__bf16)hi[3];
            *(bf16x8a*)dst = f;
        } else {
            const int mt = id - 32;
            bf16x8 f;
            #pragma unroll
            for (int j = 0; j < 7; ++j)
                f[j] = (__bf16)(qm * w1[(mt * 16 + c15) * 7 + j]);
            f[7] = (__bf16)0.0f;
            *(bf16x8a*)dst = f;
        }
    }
    if (tid < 64) {
        BL[tid]       = b1[tid];
        BL[64 + tid]  = b2[tid];
        BL[128 + tid] = b3[tid];
        BL[192 + tid] = b4[tid];
        BL[256 + tid] = b5[tid];
    }
    __syncthreads();

    const float cx = coords[2 * bn + 0];
    const float cy = coords[2 * bn + 1];
    const float* img = image + b * 3072;

    __bf16* Xw = &LDSH[ACT_H + wave * 4096];   // 2 tiles x 2048 halfwords
    const int lane_woff = c15 * 8 + (q >> 1) * 128 + (q & 1) * 4;

    f32x4 pool[4];
    #pragma unroll
    for (int mt = 0; mt < 4; ++mt) pool[mt] = (f32x4){0.f, 0.f, 0.f, 0.f};

    // leaky + cvt + C->B transform into per-tile act region (G=2 tiles)
    auto storeG = [&](f32x4 (&acc)[4][4]) {
        #pragma unroll
        for (int mt = 0; mt < 4; ++mt)
            #pragma unroll
            for (int nt = 0; nt < 4; ++nt) {
                f32x4 a = acc[mt][nt];
                bf16x4 p;
                #pragma unroll
                for (int r = 0; r < 4; ++r) {
                    float v = fmaxf(a[r], 0.1f * a[r]);
                    p[r] = (__bf16)v;
                }
                const int tile = nt >> 1, ntl = nt & 1;
                const int off = tile * 2048 + (ntl * 2 + (mt >> 1)) * 512
                              + (mt & 1) * 256 + lane_woff;
                *(bf16x4a*)&Xw[off] = p;
            }
    };

    #pragma unroll 1
    for (int t = 0; t < 4; ++t) {           // 4 passes x 64 px
        // ---- layer-1 feature B-frags (4 x 16 px)
        bf16x8 bft[4];
        #pragma unroll
        for (int nt = 0; nt < 4; ++nt) {
            const int hw = wave * 256 + t * 64 + nt * 16 + c15;
            const float i0 = img[hw];
            const float i1 = img[1024 + hw];
            const float i2 = img[2048 + hw];
            bf16x8 f;
            f[0] = (__bf16)(qm * i0);
            f[1] = (__bf16)(qm * i1);
            f[2] = (__bf16)(qm * i2);
            f[3] = (__bf16)(qm * (float)(hw >> 5) * (1.0f / 31.0f));
            f[4] = (__bf16)(qm * (float)(hw & 31) * (1.0f / 31.0f));
            f[5] = (__bf16)(qm * cx);
            f[6] = (__bf16)(qm * cy);
            f[7] = (__bf16)0.0f;
            bft[nt] = f;
        }

        // ---- layer 1
        bf16x8 a1[4];
        #pragma unroll
        for (int mt = 0; mt < 4; ++mt)
            a1[mt] = *(const bf16x8a*)&LDSH[WL_H + (32 + mt) * 512 + lane * 8];
        f32x4 acc[4][4];
        #pragma unroll
        for (int mt = 0; mt < 4; ++mt) {
            f32x4 bv = *(const f32x4a*)&BL[mt * 16 + 4 * q];
            #pragma unroll
            for (int nt = 0; nt < 4; ++nt) acc[mt][nt] = bv;
        }
        #pragma unroll
        for (int mt = 0; mt < 4; ++mt)
            #pragma unroll
            for (int nt = 0; nt < 4; ++nt)
                acc[mt][nt] = MFMA16(a1[mt], bft[nt], acc[mt][nt]);
        storeG(acc);

        // ---- layers 2..5
        #pragma unroll
        for (int l = 0; l < 4; ++l) {
            bf16x8 af[4][2];
            #pragma unroll
            for (int mt = 0; mt < 4; ++mt)
                #pragma unroll
                for (int ks = 0; ks < 2; ++ks)
                    af[mt][ks] = *(const bf16x8a*)
                        &LDSH[WL_H + (l * 8 + mt * 2 + ks) * 512 + lane * 8];
            bf16x8 bf[4][2];
            #pragma unroll
            for (int nt = 0; nt < 4; ++nt) {
                const int tile = nt >> 1, ntl = nt & 1;
                #pragma unroll
                for (int ks = 0; ks < 2; ++ks)
                    bf[nt][ks] = *(const bf16x8a*)
                        &Xw[tile * 2048 + ((ntl * 2 + ks) * 64 + lane) * 8];
            }
            #pragma unroll
            for (int mt = 0; mt < 4; ++mt) {
                f32x4 bv = *(const f32x4a*)&BL[(l + 1) * 64 + mt * 16 + 4 * q];
                #pragma unroll
                for (int nt = 0; nt < 4; ++nt) acc[mt][nt] = bv;
            }
            #pragma unroll
            for (int mt = 0; mt < 4; ++mt)
                #pragma unroll
                for (int nt = 0; nt < 4; ++nt)
                    #pragma unroll
                    for (int ks = 0; ks < 2; ++ks)
                        acc[mt][nt] = MFMA16(af[mt][ks], bf[nt][ks], acc[mt][nt]);
            if (l < 3) {
                storeG(acc);
            } else {
                #pragma unroll
                for (int mt = 0; mt < 4; ++mt)
                    #pragma unroll
                    for (int nt = 0; nt < 4; ++nt) {
                        f32x4 a = acc[mt][nt];
                        #pragma unroll
                        for (int r = 0; r < 4; ++r)
                            pool[mt][r] += fmaxf(a[r], 0.1f * a[r]);
                    }
            }
        }
    }

    // ---- pool partials -> float view of this wave's act region: [ch][col16]
    floata* Xf = (floata*)Xw;
    #pragma unroll
    for (int mt = 0; mt < 4; ++mt)
        #pragma unroll
        for (int r = 0; r < 4; ++r)
            Xf[(mt * 16 + 4 * q + r) * 16 + c15] = pool[mt][r];

    __syncthreads();

    // ---- block reduce (4 waves x 16 cols) + head + sigmoid
    if (tid < 64) {
        const int c = tid;
        float s = 0.0f;
        #pragma unroll
        for (int w = 0; w < 4; ++w) {
            const floata* P = (const floata*)&LDSH[ACT_H + w * 4096];
            #pragma unroll
            for (int c4 = 0; c4 < 4; ++c4) {
                f32x4 v = *(const f32x4a*)&P[c * 16 + c4 * 4];
                s += v[0] + v[1] + v[2] + v[3];
            }
        }
        const float p = s * (1.0f / 1024.0f);
        float s0 = wl[c] * p;
        float s1 = wl[64 + c] * p;
        float s2 = wl[128 + c] * p;
        #pragma unroll
        for (int off = 32; off > 0; off >>= 1) {
            s0 += __shfl_down(s0, off, 64);
            s1 += __shfl_down(s1, off, 64);
            s2 += __shfl_down(s2, off, 64);
        }
        if (c == 0) {
            const int n = bn & 127;
            out[(b * 3 + 0) * 128 + n] = 1.0f / (1.0f + expf(-(bl[0] + s0)));
            out[(b * 3 + 1) * 128 + n] = 1.0f / (1.0f + expf(-(bl[1] + s1)));
            out[(b * 3 + 2) * 128 + n] = 1.0f / (1.0f + expf(-(bl[2] + s2)));
        }
    }
}

extern "C" void kernel_launch(void* const* d_in, const int* in_sizes, int n_in,
                              void* d_out, int out_size, void* d_ws, size_t ws_size,
                              hipStream_t stream) {
    const float* image  = (const float*)d_in[0];
    const float* coords = (const float*)d_in[1];
    const float* w1 = (const float*)d_in[2];
    const float* b1 = (const float*)d_in[3];
    const float* w2 = (const float*)d_in[4];
    const float* b2 = (const float*)d_in[5];
    const float* w3 = (const float*)d_in[6];
    const float* b3 = (const float*)d_in[7];
    const float* w4 = (const float*)d_in[8];
    const float* b4 = (const float*)d_in[9];
    const float* w5 = (const float*)d_in[10];
    const float* b5 = (const float*)d_in[11];
    const float* wl = (const float*)d_in[12];
    const float* bl = (const float*)d_in[13];
    float* out = (float*)d_out;

    mlp_mfma_kernel<<<dim3(512), dim3(256), 0, stream>>>(
        image, coords, w1, b1, w2, b2, w3, b3, w4, b4, w5, b5, wl, bl, out);
}

// Round 7
// 110.512 us; speedup vs baseline: 2.1521x; 1.0412x over previous
//
#include <hip/hip_runtime.h>
#include <math.h>

// B=4, N=128, H=W=32, C=64.  out[b][j][n] = sigmoid(wl[j,:] . mean_hw MLP(...) + bl[j])
//
// MFMA: layers 2..5 are 64x64 GEMMs over pixel columns (16x16x32_bf16,
// M=64ch x N=16px per MFMA); layer 1 (7->64) K=32 zero-padded.
// Weights staged once per block into LDS (R6), lane-major -> ds_read_b128.
//
// R7: LOOP REORDER to kill the residual spill. R6 post-mortem: WRITE_SIZE
// 11.3MB = 86B/thread scratch = ~30 spilled VGPRs; R6's body had af(32) +
// bf(32, all 4 subtiles) + acc(64) + pool(16) ~ 160 live vs the 128 wall.
// Fix: per layer { load af(32) + bias(16) once; for tile in 0,1 { bf(16),
// acc(32), 16 MFMA, store/pool } } -> worst live ~120 <= 128, af still
// amortized over 2 tiles (same DS op count as R6).
// Act transform C->B via wave-private LDS (no barriers in main loop):
//   C: col=lane&15, row=(lane>>4)*4+reg   [m89-verified]
//   A/B: n=lane&15, k=(lane>>4)*8+j        [m120-verified]

typedef float  f32x4  __attribute__((ext_vector_type(4)));
typedef f32x4  f32x4a __attribute__((may_alias));
typedef __bf16 bf16x8 __attribute__((ext_vector_type(8)));
typedef bf16x8 bf16x8a __attribute__((may_alias));
typedef __bf16 bf16x4 __attribute__((ext_vector_type(4)));
typedef bf16x4 bf16x4a __attribute__((may_alias));
typedef float  floata __attribute__((may_alias));

#define MFMA16(a, b, c) __builtin_amdgcn_mfma_f32_16x16x32_bf16((a), (b), (c), 0, 0, 0)

// LDS halfword offsets
#define WL_H    0            // 36 frag-groups x 512 halfwords (36864 B)
#define ACT_H   18432        // 4 waves x 4096 halfwords (32768 B)

__global__ __launch_bounds__(256, 2) void mlp_mfma_kernel(
    const float* __restrict__ image,   // [4,3,32,32]
    const float* __restrict__ coords,  // [4,128,2]
    const float* __restrict__ w1, const float* __restrict__ b1,   // [64,7],[64]
    const float* __restrict__ w2, const float* __restrict__ b2,   // [64,64],[64]
    const float* __restrict__ w3, const float* __restrict__ b3,
    const float* __restrict__ w4, const float* __restrict__ b4,
    const float* __restrict__ w5, const float* __restrict__ b5,
    const float* __restrict__ wl, const float* __restrict__ bl,   // [3,64],[3]
    float* __restrict__ out)           // [4,3,128]
{
    __shared__ __align__(16) __bf16 LDSH[18432 + 16384];  // weights + acts
    __shared__ __align__(16) float  BL[320];              // biases [5][64]

    const int tid  = threadIdx.x;
    const int wave = tid >> 6;
    const int lane = tid & 63;
    const int c15  = lane & 15;
    const int q    = lane >> 4;
    const int bn   = blockIdx.x;
    const int b    = bn >> 7;

    const float qm = (q == 0) ? 1.0f : 0.0f;   // layer-1 K=32 zero-pad mask

    const float* Ws[4] = {w2, w3, w4, w5};

    // ---- stage weight A-frags into LDS, lane-major: frag id*512h + lane*8h
    //   id = l*8 + mt*2 + ks  (l=0..3 -> w2..w5), id = 32+mt -> w1
    #pragma unroll 1
    for (int i = 0; i < 9; ++i) {
        const int id = wave + i * 4;           // 4 waves cover 0..35
        __bf16* dst = &LDSH[WL_H + id * 512 + lane * 8];
        if (id < 32) {
            const int l  = id >> 3;
            const int mt = (id >> 1) & 3;
            const int ks = id & 1;
            const float* src = Ws[l] + (mt * 16 + c15) * 64 + ks * 32 + q * 8;
            f32x4 lo = *(const f32x4a*)src;
            f32x4 hi = *(const f32x4a*)(src + 4);
            bf16x8 f;
            f[0] = (__bf16)lo[0]; f[1] = (__bf16)lo[1];
            f[2] = (__bf16)lo[2]; f[3] = (__bf16)lo[3];
            f[4] = (__bf16)hi[0]; f[5] = (__bf16)hi[1];
            f[6] = (__bf16)hi[2]; f[7] = (__bf16)hi[3];
            *(bf16x8a*)dst = f;
        } else {
            const int mt = id - 32;
            bf16x8 f;
            #pragma unroll
            for (int j = 0; j < 7; ++j)
                f[j] = (__bf16)(qm * w1[(mt * 16 + c15) * 7 + j]);
            f[7] = (__bf16)0.0f;
            *(bf16x8a*)dst = f;
        }
    }
    if (tid < 64) {
        BL[tid]       = b1[tid];
        BL[64 + tid]  = b2[tid];
        BL[128 + tid] = b3[tid];
        BL[192 + tid] = b4[tid];
        BL[256 + tid] = b5[tid];
    }
    __syncthreads();

    const float cx = coords[2 * bn + 0];
    const float cy = coords[2 * bn + 1];
    const float* img = image + b * 3072;

    __bf16* Xw = &LDSH[ACT_H + wave * 4096];   // 2 tiles x 2048 halfwords
    const int lane_woff = c15 * 8 + (q >> 1) * 128 + (q & 1) * 4;

    f32x4 pool[4];
    #pragma unroll
    for (int mt = 0; mt < 4; ++mt) pool[mt] = (f32x4){0.f, 0.f, 0.f, 0.f};

    // leaky + cvt + C->B transform of one 32-px tile into its act region
    auto store_tile = [&](f32x4 (&acc)[4][2], int g) {
        #pragma unroll
        for (int mt = 0; mt < 4; ++mt)
            #pragma unroll
            for (int ntl = 0; ntl < 2; ++ntl) {
                f32x4 a = acc[mt][ntl];
                bf16x4 p;
                #pragma unroll
                for (int r = 0; r < 4; ++r) {
                    float v = fmaxf(a[r], 0.1f * a[r]);
                    p[r] = (__bf16)v;
                }
                const int off = g * 2048 + (ntl * 2 + (mt >> 1)) * 512
                              + (mt & 1) * 256 + lane_woff;
                *(bf16x4a*)&Xw[off] = p;
            }
    };

    #pragma unroll 1
    for (int t = 0; t < 4; ++t) {           // 4 passes x 64 px (2 tiles)
        // ======== layer 1 ========
        {
            bf16x8 a1[4];
            #pragma unroll
            for (int mt = 0; mt < 4; ++mt)
                a1[mt] = *(const bf16x8a*)&LDSH[WL_H + (32 + mt) * 512 + lane * 8];
            f32x4 bv[4];
            #pragma unroll
            for (int mt = 0; mt < 4; ++mt)
                bv[mt] = *(const f32x4a*)&BL[mt * 16 + 4 * q];

            #pragma unroll
            for (int g = 0; g < 2; ++g) {
                bf16x8 bft[2];
                #pragma unroll
                for (int ntl = 0; ntl < 2; ++ntl) {
                    const int hw = wave * 256 + t * 64 + g * 32 + ntl * 16 + c15;
                    const float i0 = img[hw];
                    const float i1 = img[1024 + hw];
                    const float i2 = img[2048 + hw];
                    bf16x8 f;
                    f[0] = (__bf16)(qm * i0);
                    f[1] = (__bf16)(qm * i1);
                    f[2] = (__bf16)(qm * i2);
                    f[3] = (__bf16)(qm * (float)(hw >> 5) * (1.0f / 31.0f));
                    f[4] = (__bf16)(qm * (float)(hw & 31) * (1.0f / 31.0f));
                    f[5] = (__bf16)(qm * cx);
                    f[6] = (__bf16)(qm * cy);
                    f[7] = (__bf16)0.0f;
                    bft[ntl] = f;
                }
                f32x4 acc[4][2];
                #pragma unroll
                for (int mt = 0; mt < 4; ++mt) {
                    acc[mt][0] = bv[mt]; acc[mt][1] = bv[mt];
                }
                #pragma unroll
                for (int mt = 0; mt < 4; ++mt)
                    #pragma unroll
                    for (int ntl = 0; ntl < 2; ++ntl)
                        acc[mt][ntl] = MFMA16(a1[mt], bft[ntl], acc[mt][ntl]);
                store_tile(acc, g);
            }
        }

        // ======== layers 2..5 ========
        #pragma unroll 1
        for (int l = 0; l < 4; ++l) {
            bf16x8 af[4][2];
            #pragma unroll
            for (int mt = 0; mt < 4; ++mt)
                #pragma unroll
                for (int ks = 0; ks < 2; ++ks)
                    af[mt][ks] = *(const bf16x8a*)
                        &LDSH[WL_H + (l * 8 + mt * 2 + ks) * 512 + lane * 8];
            f32x4 bv[4];
            #pragma unroll
            for (int mt = 0; mt < 4; ++mt)
                bv[mt] = *(const f32x4a*)&BL[(l + 1) * 64 + mt * 16 + 4 * q];

            #pragma unroll
            for (int g = 0; g < 2; ++g) {
                bf16x8 bf[2][2];
                #pragma unroll
                for (int ntl = 0; ntl < 2; ++ntl)
                    #pragma unroll
                    for (int ks = 0; ks < 2; ++ks)
                        bf[ntl][ks] = *(const bf16x8a*)
                            &Xw[g * 2048 + ((ntl * 2 + ks) * 64 + lane) * 8];
                f32x4 acc[4][2];
                #pragma unroll
                for (int mt = 0; mt < 4; ++mt) {
                    acc[mt][0] = bv[mt]; acc[mt][1] = bv[mt];
                }
                #pragma unroll
                for (int mt = 0; mt < 4; ++mt)
                    #pragma unroll
                    for (int ntl = 0; ntl < 2; ++ntl)
                        #pragma unroll
                        for (int ks = 0; ks < 2; ++ks)
                            acc[mt][ntl] = MFMA16(af[mt][ks], bf[ntl][ks], acc[mt][ntl]);
                if (l < 3) {
                    store_tile(acc, g);
                } else {
                    #pragma unroll
                    for (int mt = 0; mt < 4; ++mt)
                        #pragma unroll
                        for (int ntl = 0; ntl < 2; ++ntl) {
                            f32x4 a = acc[mt][ntl];
                            #pragma unroll
                            for (int r = 0; r < 4; ++r)
                                pool[mt][r] += fmaxf(a[r], 0.1f * a[r]);
                        }
                }
            }
        }
    }

    // ---- pool partials -> float view of this wave's act region: [ch][col16]
    floata* Xf = (floata*)Xw;
    #pragma unroll
    for (int mt = 0; mt < 4; ++mt)
        #pragma unroll
        for (int r = 0; r < 4; ++r)
            Xf[(mt * 16 + 4 * q + r) * 16 + c15] = pool[mt][r];

    __syncthreads();

    // ---- block reduce (4 waves x 16 cols) + head + sigmoid
    if (tid < 64) {
        const int c = tid;
        float s = 0.0f;
        #pragma unroll
        for (int w = 0; w < 4; ++w) {
            const floata* P = (const floata*)&LDSH[ACT_H + w * 4096];
            #pragma unroll
            for (int c4 = 0; c4 < 4; ++c4) {
                f32x4 v = *(const f32x4a*)&P[c * 16 + c4 * 4];
                s += v[0] + v[1] + v[2] + v[3];
            }
        }
        const float p = s * (1.0f / 1024.0f);
        float s0 = wl[c] * p;
        float s1 = wl[64 + c] * p;
        float s2 = wl[128 + c] * p;
        #pragma unroll
        for (int off = 32; off > 0; off >>= 1) {
            s0 += __shfl_down(s0, off, 64);
            s1 += __shfl_down(s1, off, 64);
            s2 += __shfl_down(s2, off, 64);
        }
        if (c == 0) {
            const int n = bn & 127;
            out[(b * 3 + 0) * 128 + n] = 1.0f / (1.0f + expf(-(bl[0] + s0)));
            out[(b * 3 + 1) * 128 + n] = 1.0f / (1.0f + expf(-(bl[1] + s1)));
            out[(b * 3 + 2) * 128 + n] = 1.0f / (1.0f + expf(-(bl[2] + s2)));
        }
    }
}

extern "C" void kernel_launch(void* const* d_in, const int* in_sizes, int n_in,
                              void* d_out, int out_size, void* d_ws, size_t ws_size,
                              hipStream_t stream) {
    const float* image  = (const float*)d_in[0];
    const float* coords = (const float*)d_in[1];
    const float* w1 = (const float*)d_in[2];
    const float* b1 = (const float*)d_in[3];
    const float* w2 = (const float*)d_in[4];
    const float* b2 = (const float*)d_in[5];
    const float* w3 = (const float*)d_in[6];
    const float* b3 = (const float*)d_in[7];
    const float* w4 = (const float*)d_in[8];
    const float* b4 = (const float*)d_in[9];
    const float* w5 = (const float*)d_in[10];
    const float* b5 = (const float*)d_in[11];
    const float* wl = (const float*)d_in[12];
    const float* bl = (const float*)d_in[13];
    float* out = (float*)d_out;

    mlp_mfma_kernel<<<dim3(512), dim3(256), 0, stream>>>(
        image, coords, w1, b1, w2, b2, w3, b3, w4, b4, w5, b5, wl, bl, out);
}

// Round 8
// 107.477 us; speedup vs baseline: 2.2129x; 1.0282x over previous
//
#include <hip/hip_runtime.h>
#include <math.h>

// B=4, N=128, H=W=32, C=64.  out[b][j][n] = sigmoid(wl[j,:] . mean_hw MLP(...) + bl[j])
//
// MFMA: layers 2..5 are 64x64 GEMMs over pixel columns (16x16x32_bf16,
// M=64ch x N=16px per MFMA); layer 1 (7->64) K=32 zero-padded.
// Weights staged once per block into LDS, lane-major -> ds_read_b128.
//
// R8: LATENCY HIDING. R7 post-mortem: spill gone (WRITE 48B, VGPR 88) but
// MfmaUtil 17.7 / VALU 44 / DS ~51% — nothing saturated: the unroll-1 layer
// loop exposes a one-layer scheduling window, so every layer serializes on
// ds_read->MFMA->ds_write->lgkm chains with only 2 waves/SIMD to cover.
// Changes (traffic-neutral, overlap-only):
//   1. Fully unroll the L2..L5 chain -> compiler pipelines next layer's
//      af/bf reads under current layer's MFMAs.
//   2. Hoist layer-1 A-frags (a1) out of the t-loop into registers.
//   3. Prefetch next t-pass's image pixels across the whole layer chain.
// VGPR headroom: 88 -> ~130 projected, cap 256 at 2 blocks/CU (LDS-bound).
// Tripwire: WRITE_SIZE must stay ~0 (no re-spill).
// Act transform C->B via wave-private LDS (no barriers in main loop):
//   C: col=lane&15, row=(lane>>4)*4+reg   [m89-verified]
//   A/B: n=lane&15, k=(lane>>4)*8+j        [m120-verified]

typedef float  f32x4  __attribute__((ext_vector_type(4)));
typedef f32x4  f32x4a __attribute__((may_alias));
typedef __bf16 bf16x8 __attribute__((ext_vector_type(8)));
typedef bf16x8 bf16x8a __attribute__((may_alias));
typedef __bf16 bf16x4 __attribute__((ext_vector_type(4)));
typedef bf16x4 bf16x4a __attribute__((may_alias));
typedef float  floata __attribute__((may_alias));

#define MFMA16(a, b, c) __builtin_amdgcn_mfma_f32_16x16x32_bf16((a), (b), (c), 0, 0, 0)

// LDS halfword offsets
#define WL_H    0            // 36 frag-groups x 512 halfwords (36864 B)
#define ACT_H   18432        // 4 waves x 4096 halfwords (32768 B)

__global__ __launch_bounds__(256, 2) void mlp_mfma_kernel(
    const float* __restrict__ image,   // [4,3,32,32]
    const float* __restrict__ coords,  // [4,128,2]
    const float* __restrict__ w1, const float* __restrict__ b1,   // [64,7],[64]
    const float* __restrict__ w2, const float* __restrict__ b2,   // [64,64],[64]
    const float* __restrict__ w3, const float* __restrict__ b3,
    const float* __restrict__ w4, const float* __restrict__ b4,
    const float* __restrict__ w5, const float* __restrict__ b5,
    const float* __restrict__ wl, const float* __restrict__ bl,   // [3,64],[3]
    float* __restrict__ out)           // [4,3,128]
{
    __shared__ __align__(16) __bf16 LDSH[18432 + 16384];  // weights + acts
    __shared__ __align__(16) float  BL[320];              // biases [5][64]

    const int tid  = threadIdx.x;
    const int wave = tid >> 6;
    const int lane = tid & 63;
    const int c15  = lane & 15;
    const int q    = lane >> 4;
    const int bn   = blockIdx.x;
    const int b    = bn >> 7;

    const float qm = (q == 0) ? 1.0f : 0.0f;   // layer-1 K=32 zero-pad mask

    const float* Ws[4] = {w2, w3, w4, w5};

    // ---- stage weight A-frags into LDS, lane-major: frag id*512h + lane*8h
    //   id = l*8 + mt*2 + ks  (l=0..3 -> w2..w5), id = 32+mt -> w1
    #pragma unroll 1
    for (int i = 0; i < 9; ++i) {
        const int id = wave + i * 4;           // 4 waves cover 0..35
        __bf16* dst = &LDSH[WL_H + id * 512 + lane * 8];
        if (id < 32) {
            const int l  = id >> 3;
            const int mt = (id >> 1) & 3;
            const int ks = id & 1;
            const float* src = Ws[l] + (mt * 16 + c15) * 64 + ks * 32 + q * 8;
            f32x4 lo = *(const f32x4a*)src;
            f32x4 hi = *(const f32x4a*)(src + 4);
            bf16x8 f;
            f[0] = (__bf16)lo[0]; f[1] = (__bf16)lo[1];
            f[2] = (__bf16)lo[2]; f[3] = (__bf16)lo[3];
            f[4] = (__bf16)hi[0]; f[5] = (__bf16)hi[1];
            f[6] = (__bf16)hi[2]; f[7] = (__bf16)hi[3];
            *(bf16x8a*)dst = f;
        } else {
            const int mt = id - 32;
            bf16x8 f;
            #pragma unroll
            for (int j = 0; j < 7; ++j)
                f[j] = (__bf16)(qm * w1[(mt * 16 + c15) * 7 + j]);
            f[7] = (__bf16)0.0f;
            *(bf16x8a*)dst = f;
        }
    }
    if (tid < 64) {
        BL[tid]       = b1[tid];
        BL[64 + tid]  = b2[tid];
        BL[128 + tid] = b3[tid];
        BL[192 + tid] = b4[tid];
        BL[256 + tid] = b5[tid];
    }
    __syncthreads();

    const float cx = coords[2 * bn + 0];
    const float cy = coords[2 * bn + 1];
    const float* img = image + b * 3072;

    __bf16* Xw = &LDSH[ACT_H + wave * 4096];   // 2 tiles x 2048 halfwords
    const int lane_woff = c15 * 8 + (q >> 1) * 128 + (q & 1) * 4;

    f32x4 pool[4];
    #pragma unroll
    for (int mt = 0; mt < 4; ++mt) pool[mt] = (f32x4){0.f, 0.f, 0.f, 0.f};

    // ---- hoisted: layer-1 A-frags in registers (loop-invariant)
    bf16x8 a1[4];
    #pragma unroll
    for (int mt = 0; mt < 4; ++mt)
        a1[mt] = *(const bf16x8a*)&LDSH[WL_H + (32 + mt) * 512 + lane * 8];

    // ---- image pixel prefetch for t=0
    float pix[2][2][3];
    #pragma unroll
    for (int g = 0; g < 2; ++g)
        #pragma unroll
        for (int ntl = 0; ntl < 2; ++ntl) {
            const int hw = wave * 256 + g * 32 + ntl * 16 + c15;
            pix[g][ntl][0] = img[hw];
            pix[g][ntl][1] = img[1024 + hw];
            pix[g][ntl][2] = img[2048 + hw];
        }

    // leaky + cvt + C->B transform of one 32-px tile into its act region
    auto store_tile = [&](f32x4 (&acc)[4][2], int g) {
        #pragma unroll
        for (int mt = 0; mt < 4; ++mt)
            #pragma unroll
            for (int ntl = 0; ntl < 2; ++ntl) {
                f32x4 a = acc[mt][ntl];
                bf16x4 p;
                #pragma unroll
                for (int r = 0; r < 4; ++r) {
                    float v = fmaxf(a[r], 0.1f * a[r]);
                    p[r] = (__bf16)v;
                }
                const int off = g * 2048 + (ntl * 2 + (mt >> 1)) * 512
                              + (mt & 1) * 256 + lane_woff;
                *(bf16x4a*)&Xw[off] = p;
            }
    };

    #pragma unroll 1
    for (int t = 0; t < 4; ++t) {           // 4 passes x 64 px (2 tiles)
        // ======== layer 1 (uses prefetched pix) ========
        {
            f32x4 bv[4];
            #pragma unroll
            for (int mt = 0; mt < 4; ++mt)
                bv[mt] = *(const f32x4a*)&BL[mt * 16 + 4 * q];

            #pragma unroll
            for (int g = 0; g < 2; ++g) {
                bf16x8 bft[2];
                #pragma unroll
                for (int ntl = 0; ntl < 2; ++ntl) {
                    const int hw = wave * 256 + t * 64 + g * 32 + ntl * 16 + c15;
                    bf16x8 f;
                    f[0] = (__bf16)(qm * pix[g][ntl][0]);
                    f[1] = (__bf16)(qm * pix[g][ntl][1]);
                    f[2] = (__bf16)(qm * pix[g][ntl][2]);
                    f[3] = (__bf16)(qm * (float)(hw >> 5) * (1.0f / 31.0f));
                    f[4] = (__bf16)(qm * (float)(hw & 31) * (1.0f / 31.0f));
                    f[5] = (__bf16)(qm * cx);
                    f[6] = (__bf16)(qm * cy);
                    f[7] = (__bf16)0.0f;
                    bft[ntl] = f;
                }
                f32x4 acc[4][2];
                #pragma unroll
                for (int mt = 0; mt < 4; ++mt) {
                    acc[mt][0] = bv[mt]; acc[mt][1] = bv[mt];
                }
                #pragma unroll
                for (int mt = 0; mt < 4; ++mt)
                    #pragma unroll
                    for (int ntl = 0; ntl < 2; ++ntl)
                        acc[mt][ntl] = MFMA16(a1[mt], bft[ntl], acc[mt][ntl]);
                store_tile(acc, g);
            }
        }

        // ---- prefetch next t's image pixels across the layer chain
        if (t < 3) {
            #pragma unroll
            for (int g = 0; g < 2; ++g)
                #pragma unroll
                for (int ntl = 0; ntl < 2; ++ntl) {
                    const int hw = wave * 256 + (t + 1) * 64 + g * 32 + ntl * 16 + c15;
                    pix[g][ntl][0] = img[hw];
                    pix[g][ntl][1] = img[1024 + hw];
                    pix[g][ntl][2] = img[2048 + hw];
                }
        }

        // ======== layers 2..5 — FULLY UNROLLED for cross-layer overlap ====
        #pragma unroll
        for (int l = 0; l < 4; ++l) {
            bf16x8 af[4][2];
            #pragma unroll
            for (int mt = 0; mt < 4; ++mt)
                #pragma unroll
                for (int ks = 0; ks < 2; ++ks)
                    af[mt][ks] = *(const bf16x8a*)
                        &LDSH[WL_H + (l * 8 + mt * 2 + ks) * 512 + lane * 8];
            f32x4 bv[4];
            #pragma unroll
            for (int mt = 0; mt < 4; ++mt)
                bv[mt] = *(const f32x4a*)&BL[(l + 1) * 64 + mt * 16 + 4 * q];

            #pragma unroll
            for (int g = 0; g < 2; ++g) {
                bf16x8 bf[2][2];
                #pragma unroll
                for (int ntl = 0; ntl < 2; ++ntl)
                    #pragma unroll
                    for (int ks = 0; ks < 2; ++ks)
                        bf[ntl][ks] = *(const bf16x8a*)
                            &Xw[g * 2048 + ((ntl * 2 + ks) * 64 + lane) * 8];
                f32x4 acc[4][2];
                #pragma unroll
                for (int mt = 0; mt < 4; ++mt) {
                    acc[mt][0] = bv[mt]; acc[mt][1] = bv[mt];
                }
                #pragma unroll
                for (int mt = 0; mt < 4; ++mt)
                    #pragma unroll
                    for (int ntl = 0; ntl < 2; ++ntl)
                        #pragma unroll
                        for (int ks = 0; ks < 2; ++ks)
                            acc[mt][ntl] = MFMA16(af[mt][ks], bf[ntl][ks], acc[mt][ntl]);
                if (l < 3) {
                    store_tile(acc, g);
                } else {
                    #pragma unroll
                    for (int mt = 0; mt < 4; ++mt)
                        #pragma unroll
                        for (int ntl = 0; ntl < 2; ++ntl) {
                            f32x4 a = acc[mt][ntl];
                            #pragma unroll
                            for (int r = 0; r < 4; ++r)
                                pool[mt][r] += fmaxf(a[r], 0.1f * a[r]);
                        }
                }
            }
        }
    }

    // ---- pool partials -> float view of this wave's act region: [ch][col16]
    floata* Xf = (floata*)Xw;
    #pragma unroll
    for (int mt = 0; mt < 4; ++mt)
        #pragma unroll
        for (int r = 0; r < 4; ++r)
            Xf[(mt * 16 + 4 * q + r) * 16 + c15] = pool[mt][r];

    __syncthreads();

    // ---- block reduce (4 waves x 16 cols) + head + sigmoid
    if (tid < 64) {
        const int c = tid;
        float s = 0.0f;
        #pragma unroll
        for (int w = 0; w < 4; ++w) {
            const floata* P = (const floata*)&LDSH[ACT_H + w * 4096];
            #pragma unroll
            for (int c4 = 0; c4 < 4; ++c4) {
                f32x4 v = *(const f32x4a*)&P[c * 16 + c4 * 4];
                s += v[0] + v[1] + v[2] + v[3];
            }
        }
        const float p = s * (1.0f / 1024.0f);
        float s0 = wl[c] * p;
        float s1 = wl[64 + c] * p;
        float s2 = wl[128 + c] * p;
        #pragma unroll
        for (int off = 32; off > 0; off >>= 1) {
            s0 += __shfl_down(s0, off, 64);
            s1 += __shfl_down(s1, off, 64);
            s2 += __shfl_down(s2, off, 64);
        }
        if (c == 0) {
            const int n = bn & 127;
            out[(b * 3 + 0) * 128 + n] = 1.0f / (1.0f + expf(-(bl[0] + s0)));
            out[(b * 3 + 1) * 128 + n] = 1.0f / (1.0f + expf(-(bl[1] + s1)));
            out[(b * 3 + 2) * 128 + n] = 1.0f / (1.0f + expf(-(bl[2] + s2)));
        }
    }
}

extern "C" void kernel_launch(void* const* d_in, const int* in_sizes, int n_in,
                              void* d_out, int out_size, void* d_ws, size_t ws_size,
                              hipStream_t stream) {
    const float* image  = (const float*)d_in[0];
    const float* coords = (const float*)d_in[1];
    const float* w1 = (const float*)d_in[2];
    const float* b1 = (const float*)d_in[3];
    const float* w2 = (const float*)d_in[4];
    const float* b2 = (const float*)d_in[5];
    const float* w3 = (const float*)d_in[6];
    const float* b3 = (const float*)d_in[7];
    const float* w4 = (const float*)d_in[8];
    const float* b4 = (const float*)d_in[9];
    const float* w5 = (const float*)d_in[10];
    const float* b5 = (const float*)d_in[11];
    const float* wl = (const float*)d_in[12];
    const float* bl = (const float*)d_in[13];
    float* out = (float*)d_out;

    mlp_mfma_kernel<<<dim3(512), dim3(256), 0, stream>>>(
        image, coords, w1, b1, w2, b2, w3, b3, w4, b4, w5, b5, wl, bl, out);
}